// Round 13
// baseline (178.868 us; speedup 1.0000x reference)
//
#include <hip/hip_runtime.h>

#define T_OUT 18
#define NAG   20000
#define EMBD  64
#define HIDD  128
#define APB   80       // agents per block; 250 * 80 = 20000
#define SH    136      // h_s agent stride (halves)
#define SE    72       // e_s agent stride (halves)
#define SG    520      // g_s agent stride (halves): 4*128 + 8 pad

typedef _Float16 half8 __attribute__((ext_vector_type(8)));
typedef _Float16 half4 __attribute__((ext_vector_type(4)));
typedef float    f32x4 __attribute__((ext_vector_type(4)));

__device__ __forceinline__ float rcpf(float x) { return __builtin_amdgcn_rcpf(x); }
__device__ __forceinline__ float sigmf(float x) { return rcpf(1.0f + __expf(-x)); }

// 1024 threads = 16 waves = 4 waves/SIMD in ONE block (compiler must fit <=128 regs/wave).
// Column-split: wave w owns gate (w>>2), cols [(w&3)*32, (w&3)*32+32) -> 2 MFMA N-tiles.
// Gate waves compute + activate gates (f32) -> g_s (f16, interleaved i,f,g,o per cell).
// ELEM phase: all 1024 threads update c (f32, reg) and h (f16, LDS), 10 cells each.
__global__
__attribute__((amdgpu_flat_work_group_size(1024, 1024)))
void lstm_seq_kernel(
    const float* __restrict__ obs,
    const float* __restrict__ w_emb,  const float* __restrict__ b_emb,
    const float* __restrict__ w_ih_e, const float* __restrict__ b_ih_e,
    const float* __restrict__ w_hh_e, const float* __restrict__ b_hh_e,
    const float* __restrict__ w_ih_d, const float* __restrict__ b_ih_d,
    const float* __restrict__ w_hh_d, const float* __restrict__ b_hh_d,
    const float* __restrict__ w_out,  const float* __restrict__ b_out,
    float* __restrict__ out)
{
  __shared__ __align__(16) _Float16 h_s[2][APB * SH];   // double-buffered hidden
  __shared__ __align__(16) _Float16 e_s[APB * SE];      // embedding (single buffer)
  __shared__ __align__(16) _Float16 g_s[APB * SG];      // activated gates, [agent][hc*4+gate]
  __shared__ float vel_s[2][APB * 2];
  __shared__ float mask_s[4][APB];

  const int tid  = threadIdx.x;
  const int wv   = tid >> 6;        // 0..15
  const int ln   = tid & 63;
  const int l15  = ln & 15;
  const int lg   = ln >> 4;
  const int a0   = blockIdx.x * APB;
  const int gate = wv >> 2;         // 0:i 1:f 2:g 3:o
  const int hcB  = (wv & 3) * 32;   // base hidden-col of this wave's tile0
  const float2* obs2 = (const float2*)obs;

  for (int i = tid; i < APB * SH; i += 1024) h_s[0][i] = (_Float16)0.f;

  const float we0 = 4.f * w_emb[ln * 2 + 0];
  const float we1 = 4.f * w_emb[ln * 2 + 1];
  const float be  = b_emb[ln];

  // prologue: vel/mask for steps 0,1; carry obs(2)
  float oAx = 0.f, oAy = 0.f;
  if (tid < APB) {
    int a = a0 + tid;
    float2 o0 = obs2[0 * NAG + a];
    float2 o1 = obs2[1 * NAG + a];
    float2 o2 = obs2[2 * NAG + a];
    bool k0 = !__builtin_isnan(o0.x) && !__builtin_isnan(o1.x);
    bool k1 = !__builtin_isnan(o1.x) && !__builtin_isnan(o2.x);
    mask_s[0][tid] = k0 ? 1.f : 0.f;
    vel_s[0][tid * 2 + 0] = k0 ? (o1.x - o0.x) : 0.f;
    vel_s[0][tid * 2 + 1] = k0 ? (o1.y - o0.y) : 0.f;
    mask_s[1][tid] = k1 ? 1.f : 0.f;
    vel_s[1][tid * 2 + 0] = k1 ? (o2.x - o1.x) : 0.f;
    vel_s[1][tid * 2 + 1] = k1 ? (o2.y - o1.y) : 0.f;
    oAx = o2.x; oAy = o2.y;
  }

  // ---- weight fragments: 2 N-tiles per wave ----
  half8 fih[2][2];   // [tile][ks]  rows wv*32 + tile*16 + l15, K=64
  half8 fhh[2][4];   // [tile][ks]  K=128
  half8 fout[4];
  float bsum[2], bo;

  {
    int j = l15;
    #pragma unroll
    for (int ks = 0; ks < 4; ks++) {
      half8 v;
      #pragma unroll
      for (int q = 0; q < 8; q++) {
        float x = (j < 5) ? w_out[j * HIDD + ks * 32 + lg * 8 + q] : 0.f;
        v[q] = (_Float16)x;
      }
      fout[ks] = v;
    }
    bo = (j < 5) ? b_out[j] : 0.f;
  }

  auto load_phase = [&](const float* wih, const float* bih,
                        const float* whh, const float* bhh) {
    #pragma unroll
    for (int tile = 0; tile < 2; tile++) {
      int row = wv * 32 + tile * 16 + l15;
      #pragma unroll
      for (int ks = 0; ks < 2; ks++) {
        const float* p = wih + row * EMBD + ks * 32 + lg * 8;
        half8 v;
        #pragma unroll
        for (int q = 0; q < 8; q++) v[q] = (_Float16)p[q];
        fih[tile][ks] = v;
      }
      #pragma unroll
      for (int ks = 0; ks < 4; ks++) {
        const float* p = whh + row * HIDD + ks * 32 + lg * 8;
        half8 v;
        #pragma unroll
        for (int q = 0; q < 8; q++) v[q] = (_Float16)p[q];
        fhh[tile][ks] = v;
      }
      bsum[tile] = bih[row] + bhh[row];
    }
  };

  auto emb_compute = [&](int vb) {
    // 80 rows x 64 cols / 1024 threads = 5 rows per thread (row = wv+16k, col = ln)
    #pragma unroll
    for (int k = 0; k < 5; k++) {
      int a = wv + 16 * k;
      float vx = vel_s[vb][a * 2], vy = vel_s[vb][a * 2 + 1];
      float e = fmaf(vx, we0, fmaf(vy, we1, be));
      e_s[a * SE + ln] = (_Float16)fmaxf(e, 0.f);
    }
  };

  load_phase(w_ih_e, b_ih_e, w_hh_e, b_hh_e);
  __syncthreads();           // h zero, vel(0..1), mask(0..1) visible
  emb_compute(0);            // e_s = emb(0)
  __syncthreads();

  float c_r[10];             // cell state: cell (a = (tid>>7)+8k, hc = tid&127)
  #pragma unroll
  for (int k = 0; k < 10; k++) c_r[k] = 0.f;

  const int aBase = tid >> 7;     // 0..7
  const int hc    = tid & 127;

  #pragma unroll 1
  for (int t = 0; t < T_OUT; t++) {
    if (t == 8) load_phase(w_ih_d, b_ih_d, w_hh_d, b_hh_d);

    const int idx  = t & 1;
    const int nidx = idx ^ 1;
    const int msC  = t & 3;          // mask(t)
    const int msP  = (t + 3) & 3;    // mask(t-1)

    // issue obs(t+3) early
    float n3x = 0.f, n3y = 0.f;
    if (t + 2 < T_OUT && tid < APB) {
      float2 o = obs2[(size_t)(t + 3) * NAG + a0 + tid];
      n3x = o.x; n3y = o.y;
    }

    // ---- phase 1: gate MFMAs + in-register activation -> g_s ----
    #pragma unroll
    for (int m = 0; m < 5; m++) {
      f32x4 A0 = f32x4{bsum[0], bsum[0], bsum[0], bsum[0]};
      f32x4 A1 = f32x4{bsum[1], bsum[1], bsum[1], bsum[1]};
      #pragma unroll
      for (int ks = 0; ks < 2; ks++) {
        half8 av = *(const half8*)&e_s[(m * 16 + l15) * SE + ks * 32 + lg * 8];
        A0 = __builtin_amdgcn_mfma_f32_16x16x32_f16(av, fih[0][ks], A0, 0, 0, 0);
        A1 = __builtin_amdgcn_mfma_f32_16x16x32_f16(av, fih[1][ks], A1, 0, 0, 0);
      }
      #pragma unroll
      for (int ks = 0; ks < 4; ks++) {
        half8 av = *(const half8*)&h_s[idx][(m * 16 + l15) * SH + ks * 32 + lg * 8];
        A0 = __builtin_amdgcn_mfma_f32_16x16x32_f16(av, fhh[0][ks], A0, 0, 0, 0);
        A1 = __builtin_amdgcn_mfma_f32_16x16x32_f16(av, fhh[1][ks], A1, 0, 0, 0);
      }

      float v[8] = {A0[0], A0[1], A0[2], A0[3], A1[0], A1[1], A1[2], A1[3]};
      float r[8];
      if (gate == 2) {               // tanh (wave-uniform branch)
        float d[8];
        #pragma unroll
        for (int i = 0; i < 8; i++) d[i] = 1.f + __expf(-2.f * v[i]);
        #pragma unroll
        for (int i = 0; i < 8; i += 2) {
          float p = rcpf(d[i] * d[i + 1]);
          r[i]     = fmaf(2.f, d[i + 1] * p, -1.f);
          r[i + 1] = fmaf(2.f, d[i] * p, -1.f);
        }
      } else {                       // sigmoid
        float d[8];
        #pragma unroll
        for (int i = 0; i < 8; i++) d[i] = 1.f + __expf(-v[i]);
        #pragma unroll
        for (int i = 0; i < 8; i += 2) {
          float p = rcpf(d[i] * d[i + 1]);
          r[i]     = d[i + 1] * p;
          r[i + 1] = d[i] * p;
        }
      }
      #pragma unroll
      for (int i = 0; i < 8; i++) {
        int agent = m * 16 + lg * 4 + (i & 3);
        int hcw   = hcB + (i >> 2) * 16 + l15;
        g_s[agent * SG + hcw * 4 + gate] = (_Float16)r[i];
      }
    }

    // ---- out-head for step t-1 (waves 11..15, reads stable h_s[idx]) ----
    if (t > 0 && wv >= 11) {
      int mo = wv - 11;
      f32x4 oa = f32x4{bo, bo, bo, bo};
      #pragma unroll
      for (int ks = 0; ks < 4; ks++) {
        half8 av = *(const half8*)&h_s[idx][(mo * 16 + l15) * SH + ks * 32 + lg * 8];
        oa = __builtin_amdgcn_mfma_f32_16x16x32_f16(av, fout[ks], oa, 0, 0, 0);
      }
      int j = l15;
      #pragma unroll
      for (int r = 0; r < 4; r++) {
        int agent = mo * 16 + lg * 4 + r;
        float mk = mask_s[msP][agent];
        float nv = oa[r];
        float y;
        if (j < 2)      y = nv;
        else if (j < 4) y = 0.01f + 0.2f * sigmf(nv);
        else            y = 0.7f * sigmf(nv);
        if (j < 5) out[((size_t)(t - 1) * NAG + a0 + agent) * 5 + j] = y * mk;
      }
    }

    __syncthreads();   // A: g_s complete; e_s / h_s[idx] MFMA reads done

    // ---- phase 2: c/h update (all 1024 threads, 10 cells each) ----
    #pragma unroll
    for (int k = 0; k < 10; k++) {
      int a = aBase + 8 * k;
      half4 g4 = *(const half4*)&g_s[a * SG + hc * 4];
      float iv = (float)g4[0], fv = (float)g4[1];
      float gv = (float)g4[2], ov = (float)g4[3];
      float c2 = fmaf(fv, c_r[k], iv * gv);
      float th = fmaf(2.f, rcpf(1.f + __expf(-2.f * c2)), -1.f);
      float mk = mask_s[msC][a];
      bool on = (mk != 0.f);
      c_r[k] = on ? c2 : c_r[k];
      _Float16 hold = h_s[idx][a * SH + hc];
      h_s[nidx][a * SH + hc] = on ? (_Float16)(ov * th) : hold;
    }

    // ---- emb(t+1) from vel(t+1) ----
    if (t + 1 < T_OUT) emb_compute((t + 1) & 1);

    // ---- publish vel(t+2)/mask(t+2) ----
    if (t + 2 < T_OUT && tid < APB) {
      bool ok = !__builtin_isnan(oAx) && !__builtin_isnan(n3x);
      mask_s[(t + 2) & 3][tid] = ok ? 1.f : 0.f;
      vel_s[t & 1][tid * 2 + 0] = ok ? (n3x - oAx) : 0.f;
      vel_s[t & 1][tid * 2 + 1] = ok ? (n3y - oAy) : 0.f;
      oAx = n3x; oAy = n3y;
    }

    __syncthreads();   // B: h(t+1), e(t+1), vel/mask published
  }

  // ---- epilogue: out-head for step 17 (h(18) in h_s[0]) ----
  if (wv >= 11) {
    int mo = wv - 11;
    f32x4 oa = f32x4{bo, bo, bo, bo};
    #pragma unroll
    for (int ks = 0; ks < 4; ks++) {
      half8 av = *(const half8*)&h_s[T_OUT & 1][(mo * 16 + l15) * SH + ks * 32 + lg * 8];
      oa = __builtin_amdgcn_mfma_f32_16x16x32_f16(av, fout[ks], oa, 0, 0, 0);
    }
    int j = l15;
    #pragma unroll
    for (int r = 0; r < 4; r++) {
      int agent = mo * 16 + lg * 4 + r;
      float mk = mask_s[(T_OUT - 1) & 3][agent];
      float nv = oa[r];
      float y;
      if (j < 2)      y = nv;
      else if (j < 4) y = 0.01f + 0.2f * sigmf(nv);
      else            y = 0.7f * sigmf(nv);
      if (j < 5) out[((size_t)(T_OUT - 1) * NAG + a0 + agent) * 5 + j] = y * mk;
    }
  }
}

extern "C" void kernel_launch(void* const* d_in, const int* in_sizes, int n_in,
                              void* d_out, int out_size, void* d_ws, size_t ws_size,
                              hipStream_t stream) {
  const float* obs    = (const float*)d_in[0];
  const float* w_emb  = (const float*)d_in[2];
  const float* b_emb  = (const float*)d_in[3];
  const float* w_ih_e = (const float*)d_in[4];
  const float* b_ih_e = (const float*)d_in[5];
  const float* w_hh_e = (const float*)d_in[6];
  const float* b_hh_e = (const float*)d_in[7];
  const float* w_ih_d = (const float*)d_in[8];
  const float* b_ih_d = (const float*)d_in[9];
  const float* w_hh_d = (const float*)d_in[10];
  const float* b_hh_d = (const float*)d_in[11];
  const float* w_out  = (const float*)d_in[12];
  const float* b_out  = (const float*)d_in[13];
  float* out = (float*)d_out;

  lstm_seq_kernel<<<dim3(250), dim3(1024), 0, stream>>>(
      obs, w_emb, b_emb, w_ih_e, b_ih_e, w_hh_e, b_hh_e,
      w_ih_d, b_ih_d, w_hh_d, b_hh_d, w_out, b_out, out);
}